// Round 8
// baseline (7904.297 us; speedup 1.0000x reference)
//
#include <hip/hip_runtime.h>
#include <math.h>

// ---------------------------------------------------------------------------
// MDN-RNN round 8: persistent kernel, bf16 hi/lo plane exchange, tiled MFMA.
//
// grid 256 WGs x 512 thr. WG (ut=wg>>4, g=wg&15): units u0..+15, batches
// b0..+15, head batch bhead=b0+ut. Cluster = 16 WGs sharing g.
//
// h exchange: two u16 planes (bf16 hi, bf16 lo) in [b][u] layout (packed as
// u32 pairs). Producer stores via lane-pair pack; consumer stage = pure u64
// copy global->LDS into MFMA frag layout [sk][kg][n][j] (no unpack VALU).
//
// MFMA row packing: tile t = 16 rows (4 units x 4 gates): m = usub*4 + gate.
//   wave0: hi-pass tiles 0,1   (Whi x hhi + Whi x hlo)   16 reads, 32 MFMA
//   wave1: hi-pass tiles 2,3
//   wave2: lo-pass tiles 0,1   (Wlo x hhi)                8 reads, 16 MFMA
//   wave3: lo-pass tiles 2,3
//   wave4: x-pass  tiles 0-3   (3 hi/lo combos)           4 reads, 24 MFMA
//   waves 5-7 (+w4 tail): L1 (VALU) concurrently in C.
// C-frag: col=lane&15=batch, row=(lane>>4)*4+reg -> reg = GATE (i,f,g,o).
//
// Phases (3 barriers): A [L2/L3/FIN (prev-state) + per-wave poll + stage +
// hcol] | C [MFMA + L1] | E [pointwise + plane stores + hid1 combine + xF].
// Lags (as r7): L1: h_s | L2: h_{s-1} | L3: h_{s-2} | FIN -> t = s-4.
// ---------------------------------------------------------------------------

#define NOUT 1023
#define KK   5
#define MEANBASE (256 * NOUT * KK)
#define VARBASE  (MEANBASE + 256 * NOUT * KK * 32)

// u32-index offsets in ws
#define OFF_HIP(par) ((par) * 32768)            // hi plane [b][u/2] u32
#define OFF_LOP(par) (65536 + (par) * 32768)    // lo plane
#define OFF_FLG      131072
// float-index offsets in ws
#define OFF_W1T      131136                     // [256k][128ch]
#define OFF_W2T      163904                     // [100k][128ch]
#define OFF_W3T      176704                     // [100k][192ch]

typedef __attribute__((ext_vector_type(8))) short s8t;
typedef __attribute__((ext_vector_type(4))) float f4t;

__device__ __forceinline__ float sigf(float v) { return 1.0f / (1.0f + expf(-v)); }
__device__ __forceinline__ unsigned short f2bf(float f) {
    unsigned u = __float_as_uint(f);
    u += 0x7fffu + ((u >> 16) & 1u);
    return (unsigned short)(u >> 16);
}
__device__ __forceinline__ float bf2f(unsigned short h) {
    return __uint_as_float(((unsigned)h) << 16);
}

// ------------------- one-time: transposed head weights ----------------------
__global__ __launch_bounds__(256) void prep_pack(
    const float* __restrict__ W1, const float* __restrict__ W2,
    const float* __restrict__ W3, float* __restrict__ ws)
{
    const int idx = blockIdx.x * 256 + threadIdx.x;
    if (idx < 32768) {
        int k = idx >> 7, c = idx & 127;
        if (c < 100) ws[OFF_W1T + idx] = W1[c * 256 + k];
    } else if (idx < 45568) {
        int r = idx - 32768, k = r >> 7, c = r & 127;
        if (c < 100) ws[OFF_W2T + r] = W2[c * 100 + k];
    } else if (idx < 64768) {
        int r = idx - 45568, k = r / 192, c = r - k * 192;
        if (c < 170) ws[OFF_W3T + r] = W3[c * 100 + k];
    }
}

// ------------------------------ persistent kernel ---------------------------
__global__ __launch_bounds__(512, 1) void mdn_rnn_persist(
    const float* __restrict__ x,
    const float* __restrict__ W_ih, const float* __restrict__ W_hh,
    const float* __restrict__ b_ih, const float* __restrict__ b_hh,
    const float* __restrict__ b1, const float* __restrict__ b2,
    const float* __restrict__ b3,
    float* __restrict__ ws, float* __restrict__ out)
{
    __shared__ __align__(16) unsigned short hFhi[4096], hFlo[4096]; // [sk8][kg4][n16][j8]
    __shared__ __align__(16) unsigned short xFh[2][1024], xFl[2][1024];
    __shared__ __align__(16) float hcolL[256];
    __shared__ f4t  gC4[780];          // slot = (pass*4+tile)*65 + lanepos
    __shared__ float ph1[2][104];
    __shared__ float hid1L[2][104], hid2L[2][104], oL[2][176];
    __shared__ f4t  bgv[16];

    const int tid = threadIdx.x;
    const int wg  = blockIdx.x;
    const int ut = wg >> 4, g = wg & 15;
    const int u0 = ut * 16, b0 = g * 16, bhead = b0 + ut;
    const int wave = tid >> 6, lane = tid & 63;

    unsigned* ws32 = (unsigned*)ws;
    unsigned* flags = ws32 + OFF_FLG;

    // x prefetch mapping (tid < 280: 2 elems of 16b x 35j)
    const int e0 = tid * 2, pb0 = e0 / 35, pj0 = e0 - pb0 * 35;
    const int e1 = e0 + 1, pb1 = e1 / 35, pj1 = e1 - pb1 * 35;

    // ---- A-fragments (registers, persistent). Rows m = usub*4 + gate. ----
    s8t aW0[8], aW1[8];
    {
        const int m = lane & 15, usub = m >> 2, gg2 = m & 3;
        const int kb8 = (lane >> 4) * 8;
        if (wave < 4) {
            const bool low = (wave >= 2);
            const int tt0 = (wave & 1) * 2;
            #pragma unroll
            for (int t2 = 0; t2 < 2; ++t2) {
                const size_t row = (size_t)(gg2 * 256 + u0 + (tt0 + t2) * 4 + usub) * 256;
                #pragma unroll
                for (int sk = 0; sk < 8; ++sk) {
                    s8t v;
                    #pragma unroll
                    for (int j = 0; j < 8; ++j) {
                        float wv = W_hh[row + sk * 32 + kb8 + j];
                        unsigned short hi = f2bf(wv);
                        v[j] = low ? (short)f2bf(wv - bf2f(hi)) : (short)hi;
                    }
                    if (t2 == 0) aW0[sk] = v; else aW1[sk] = v;
                }
            }
        } else if (wave == 4) {
            #pragma unroll
            for (int t2 = 0; t2 < 4; ++t2) {
                const size_t row = (size_t)(gg2 * 256 + u0 + t2 * 4 + usub) * 35;
                #pragma unroll
                for (int sk = 0; sk < 2; ++sk) {
                    s8t vh, vl;
                    #pragma unroll
                    for (int j = 0; j < 8; ++j) {
                        int k = sk * 32 + kb8 + j;
                        float wv = (k < 35) ? W_ih[row + k] : 0.f;
                        unsigned short hi = f2bf(wv);
                        vh[j] = (short)hi;
                        vl[j] = (short)f2bf(wv - bf2f(hi));
                    }
                    aW0[t2 * 2 + sk] = vh;   // x hi frags
                    aW1[t2 * 2 + sk] = vl;   // x lo frags
                }
            }
        } else {
            #pragma unroll
            for (int i2 = 0; i2 < 8; ++i2) { aW0[i2] = (s8t)0; aW1[i2] = (s8t)0; }
        }
    }
    if (tid < 16)
        bgv[tid] = (f4t){ b_ih[u0 + tid]       + b_hh[u0 + tid],
                          b_ih[256 + u0 + tid] + b_hh[256 + u0 + tid],
                          b_ih[512 + u0 + tid] + b_hh[512 + u0 + tid],
                          b_ih[768 + u0 + tid] + b_hh[768 + u0 + tid] };
    // prologue: x_0 -> xF[0]
    if (tid < 280) {
        float v0 = x[(size_t)(b0 + pb0) * 35840 + pj0];
        float v1 = x[(size_t)(b0 + pb1) * 35840 + pj1];
        int sa = (pj0 >> 5) * 512 + ((pj0 >> 3) & 3) * 128 + pb0 * 8 + (pj0 & 7);
        unsigned short h0 = f2bf(v0);
        xFh[0][sa] = h0; xFl[0][sa] = f2bf(v0 - bf2f(h0));
        int sb = (pj1 >> 5) * 512 + ((pj1 >> 3) & 3) * 128 + pb1 * 8 + (pj1 & 7);
        unsigned short h1 = f2bf(v1);
        xFh[0][sb] = h1; xFl[0][sb] = f2bf(v1 - bf2f(h1));
    }
    __syncthreads();

    float c_reg = 0.0f;

    // stage decode: thread -> (plane, skh, kg, n, jq)
    const int sp = tid >> 8;
    const int r8 = tid & 255;
    const int sskh = r8 >> 7, skg = (r8 >> 5) & 3, sn = (r8 >> 1) & 15, sjq = r8 & 1;

    for (int s = 0; s < 1027; ++s) {
        const int parC = s & 1, parN = parC ^ 1;

        // ================= A =================
        float xpf0 = 0.f, xpf1 = 0.f;
        const bool dopf = (s < 1022) && (tid < 280);
        if (dopf) {
            const float* xp = x + (size_t)(s + 1) * 35;
            xpf0 = __builtin_nontemporal_load(xp + (size_t)(b0 + pb0) * 35840 + pj0);
            xpf1 = __builtin_nontemporal_load(xp + (size_t)(b0 + pb1) * 35840 + pj1);
        }
        if (wave == 0) {                                   // L2 (dual channel)
            if (s >= 2 && s <= 1024) {
                const float* W2T = ws + OFF_W2T;
                {
                    const int ch = lane;
                    float a0 = 0.f, a1 = 0.f;
                    #pragma unroll 10
                    for (int k = 0; k < 50; ++k) {
                        a0 = fmaf(W2T[k * 128 + ch],        hid1L[parN][k],      a0);
                        a1 = fmaf(W2T[(k + 50) * 128 + ch], hid1L[parN][k + 50], a1);
                    }
                    hid2L[parC][ch] = fmaxf(a0 + a1 + b2[ch], 0.f);
                }
                if (lane < 36) {
                    const int ch = 64 + lane;
                    float a0 = 0.f, a1 = 0.f;
                    #pragma unroll 10
                    for (int k = 0; k < 50; ++k) {
                        a0 = fmaf(W2T[k * 128 + ch],        hid1L[parN][k],      a0);
                        a1 = fmaf(W2T[(k + 50) * 128 + ch], hid1L[parN][k + 50], a1);
                    }
                    hid2L[parC][ch] = fmaxf(a0 + a1 + b2[ch], 0.f);
                }
            }
        } else if (wave <= 3) {                            // L3 + FIN
            const int ch3 = (wave == 1) ? lane : (wave == 2) ? 64 + lane : 128 + lane;
            if ((wave < 3 || lane < 42) && s >= 3 && s <= 1025) {
                const float* W3T = ws + OFF_W3T;
                float a0 = 0.f, a1 = 0.f;
                #pragma unroll 10
                for (int k = 0; k < 50; ++k) {
                    a0 = fmaf(W3T[k * 192 + ch3],        hid2L[parN][k],      a0);
                    a1 = fmaf(W3T[(k + 50) * 192 + ch3], hid2L[parN][k + 50], a1);
                }
                oL[parC][ch3] = a0 + a1 + b3[ch3];
            }
            const int chf = (wave == 1) ? lane : (wave == 2) ? 57 + lane : 114 + lane;
            const bool fok = (wave < 3) ? (lane < 57) : (lane < 56);
            if (fok && s >= 4) {                           // FIN: t = s-4
                const int t = s - 4;
                float m5 = oL[parN][0];
                #pragma unroll
                for (int k = 1; k < KK; ++k) m5 = fmaxf(m5, oL[parN][k]);
                float den = 0.f;
                #pragma unroll
                for (int k = 0; k < KK; ++k) den += expf(oL[parN][k] - m5);
                float v = oL[parN][chf];
                if (chf < KK)
                    out[(size_t)bhead * 5115 + (size_t)t * 5 + chf] = expf(v - m5) / den;
                else if (chf < 2 * KK)
                    out[VARBASE + (size_t)bhead * 5115 + (size_t)t * 5 + (chf - 5)] = expf(v);
                else
                    out[MEANBASE + ((size_t)bhead * NOUT + t) * 160 + (chf - 10)] = v;
            }
        }
        // per-wave poll of cluster flags
        if (s >= 1 && s <= 1023 && lane < 16) {
            while (__hip_atomic_load(&flags[g * 16 + lane], __ATOMIC_RELAXED,
                                     __HIP_MEMORY_SCOPE_AGENT) < (unsigned)s)
                __builtin_amdgcn_s_sleep(1);
        }
        // stage h_s planes -> frag LDS (pure copy)
        if (s <= 1022) {
            const unsigned long long* src = (const unsigned long long*)
                (ws32 + (sp ? OFF_LOP(parC) : OFF_HIP(parC)))
                + (size_t)(b0 + sn) * 64 + skg * 2 + sjq;
            unsigned short* dst = sp ? hFlo : hFhi;
            unsigned long long q[4];
            #pragma unroll
            for (int i = 0; i < 4; ++i)
                q[i] = __hip_atomic_load(src + (sskh * 4 + i) * 8, __ATOMIC_RELAXED,
                                         __HIP_MEMORY_SCOPE_AGENT);
            #pragma unroll
            for (int i = 0; i < 4; ++i)
                *(unsigned long long*)&dst[(sskh * 4 + i) * 512 + skg * 128 + sn * 8 + sjq * 4] = q[i];
        }
        // hcol: fp32 h_s column for this WG's head batch
        if (wave == 4 && s <= 1023) {
            const unsigned long long* hq =
                (const unsigned long long*)(ws32 + OFF_HIP(parC)) + (size_t)bhead * 64 + lane;
            const unsigned long long* lq =
                (const unsigned long long*)(ws32 + OFF_LOP(parC)) + (size_t)bhead * 64 + lane;
            unsigned long long hv = __hip_atomic_load(hq, __ATOMIC_RELAXED, __HIP_MEMORY_SCOPE_AGENT);
            unsigned long long lv = __hip_atomic_load(lq, __ATOMIC_RELAXED, __HIP_MEMORY_SCOPE_AGENT);
            f4t r;
            r.x = bf2f((unsigned short)hv)         + bf2f((unsigned short)lv);
            r.y = bf2f((unsigned short)(hv >> 16)) + bf2f((unsigned short)(lv >> 16));
            r.z = bf2f((unsigned short)(hv >> 32)) + bf2f((unsigned short)(lv >> 32));
            r.w = bf2f((unsigned short)(hv >> 48)) + bf2f((unsigned short)(lv >> 48));
            *(f4t*)&hcolL[lane * 4] = r;
        }
        __syncthreads();  // syncStage

        // ================= C: MFMA + L1 =================
        if (s <= 1022 && wave < 4) {
            f4t acc0 = (f4t){0.f, 0.f, 0.f, 0.f}, acc1 = acc0;
            const int fo = lane * 8;
            if (wave < 2) {        // hi-pass: Whi x hhi + Whi x hlo
                #pragma unroll
                for (int sk = 0; sk < 8; ++sk) {
                    s8t bh = *(const s8t*)&hFhi[sk * 512 + fo];
                    acc0 = __builtin_amdgcn_mfma_f32_16x16x32_bf16(aW0[sk], bh, acc0, 0, 0, 0);
                    acc1 = __builtin_amdgcn_mfma_f32_16x16x32_bf16(aW1[sk], bh, acc1, 0, 0, 0);
                    s8t bl = *(const s8t*)&hFlo[sk * 512 + fo];
                    acc0 = __builtin_amdgcn_mfma_f32_16x16x32_bf16(aW0[sk], bl, acc0, 0, 0, 0);
                    acc1 = __builtin_amdgcn_mfma_f32_16x16x32_bf16(aW1[sk], bl, acc1, 0, 0, 0);
                }
            } else {               // lo-pass: Wlo x hhi
                #pragma unroll
                for (int sk = 0; sk < 8; ++sk) {
                    s8t bh = *(const s8t*)&hFhi[sk * 512 + fo];
                    acc0 = __builtin_amdgcn_mfma_f32_16x16x32_bf16(aW0[sk], bh, acc0, 0, 0, 0);
                    acc1 = __builtin_amdgcn_mfma_f32_16x16x32_bf16(aW1[sk], bh, acc1, 0, 0, 0);
                }
            }
            const int ps = (wave < 2) ? 0 : 1;
            const int tt0 = (wave & 1) * 2;
            gC4[(ps * 4 + tt0) * 65 + lane]       = acc0;
            gC4[(ps * 4 + tt0 + 1) * 65 + lane]   = acc1;
        }
        if (s <= 1022 && wave == 4) {              // x-pass, 4 tiles
            f4t a0 = (f4t){0.f,0.f,0.f,0.f}, a1 = a0, a2 = a0, a3 = a0;
            const int fo = lane * 8;
            #pragma unroll
            for (int sk = 0; sk < 2; ++sk) {
                s8t xh = *(const s8t*)&xFh[parC][sk * 512 + fo];
                s8t xl = *(const s8t*)&xFl[parC][sk * 512 + fo];
                a0 = __builtin_amdgcn_mfma_f32_16x16x32_bf16(aW0[0 + sk], xh, a0, 0, 0, 0);
                a0 = __builtin_amdgcn_mfma_f32_16x16x32_bf16(aW0[0 + sk], xl, a0, 0, 0, 0);
                a0 = __builtin_amdgcn_mfma_f32_16x16x32_bf16(aW1[0 + sk], xh, a0, 0, 0, 0);
                a1 = __builtin_amdgcn_mfma_f32_16x16x32_bf16(aW0[2 + sk], xh, a1, 0, 0, 0);
                a1 = __builtin_amdgcn_mfma_f32_16x16x32_bf16(aW0[2 + sk], xl, a1, 0, 0, 0);
                a1 = __builtin_amdgcn_mfma_f32_16x16x32_bf16(aW1[2 + sk], xh, a1, 0, 0, 0);
                a2 = __builtin_amdgcn_mfma_f32_16x16x32_bf16(aW0[4 + sk], xh, a2, 0, 0, 0);
                a2 = __builtin_amdgcn_mfma_f32_16x16x32_bf16(aW0[4 + sk], xl, a2, 0, 0, 0);
                a2 = __builtin_amdgcn_mfma_f32_16x16x32_bf16(aW1[4 + sk], xh, a2, 0, 0, 0);
                a3 = __builtin_amdgcn_mfma_f32_16x16x32_bf16(aW0[6 + sk], xh, a3, 0, 0, 0);
                a3 = __builtin_amdgcn_mfma_f32_16x16x32_bf16(aW0[6 + sk], xl, a3, 0, 0, 0);
                a3 = __builtin_amdgcn_mfma_f32_16x16x32_bf16(aW1[6 + sk], xh, a3, 0, 0, 0);
            }
            gC4[(8 + 0) * 65 + lane] = a0;
            gC4[(8 + 1) * 65 + lane] = a1;
            gC4[(8 + 2) * 65 + lane] = a2;
            gC4[(8 + 3) * 65 + lane] = a3;
        }
        if (s >= 1 && s <= 1023) {                 // L1 on w5-7 + w4 tail
            const int a1i = (wave >= 5) ? (wave - 5) * 64 + lane
                          : (wave == 4 && lane >= 56) ? 192 + (lane - 56) : 256;
            if (a1i < 200) {
                const int kh = (a1i >= 100), ch = a1i - kh * 100;
                const int kb = kh * 128;
                const float* Wp = ws + OFF_W1T + ch;
                float s0 = 0.f, s1 = 0.f;
                #pragma unroll 16
                for (int i = 0; i < 64; ++i) {
                    s0 = fmaf(Wp[(kb + i) * 128],      hcolL[kb + i],      s0);
                    s1 = fmaf(Wp[(kb + 64 + i) * 128], hcolL[kb + 64 + i], s1);
                }
                ph1[kh][ch] = s0 + s1;
            }
        }
        __syncthreads();  // syncC

        // ================= E =================
        if (s <= 1022 && tid < 256) {
            const int fu = tid & 15, fb = tid >> 4;
            const int tile = fu >> 2, l2 = (fu & 3) * 16 + fb;
            f4t p0 = gC4[(0 + tile) * 65 + l2];
            f4t p1 = gC4[(4 + tile) * 65 + l2];
            f4t p2 = gC4[(8 + tile) * 65 + l2];
            f4t bb = bgv[fu];
            float gi  = p0.x + p1.x + p2.x + bb.x;
            float gf2 = p0.y + p1.y + p2.y + bb.y;
            float gg3 = p0.z + p1.z + p2.z + bb.z;
            float go  = p0.w + p1.w + p2.w + bb.w;
            float iv = sigf(gi), fv = sigf(gf2);
            float gvv = tanhf(gg3), ov = sigf(go);
            c_reg = fv * c_reg + iv * gvv;
            float hval = ov * tanhf(c_reg);
            unsigned hi16 = f2bf(hval);
            unsigned lo16 = f2bf(hval - bf2f((unsigned short)hi16));
            unsigned phi = (unsigned)__shfl_xor((int)hi16, 1);
            unsigned plo = (unsigned)__shfl_xor((int)lo16, 1);
            if (!(fu & 1)) {
                const unsigned idx = (unsigned)(b0 + fb) * 128u + (unsigned)((u0 + fu) >> 1);
                __hip_atomic_store(ws32 + OFF_HIP(parN) + idx, hi16 | (phi << 16),
                                   __ATOMIC_RELAXED, __HIP_MEMORY_SCOPE_AGENT);
                __hip_atomic_store(ws32 + OFF_LOP(parN) + idx, lo16 | (plo << 16),
                                   __ATOMIC_RELAXED, __HIP_MEMORY_SCOPE_AGENT);
            }
        }
        if (s >= 1 && s <= 1023 && tid >= 256 && tid < 356) {   // hid1 combine
            const int c = tid - 256;
            hid1L[parC][c] = fmaxf(ph1[0][c] + ph1[1][c] + b1[c], 0.f);
        }
        if (dopf) {                                              // x_{s+1} -> xF[parN]
            int sa = (pj0 >> 5) * 512 + ((pj0 >> 3) & 3) * 128 + pb0 * 8 + (pj0 & 7);
            unsigned short h0 = f2bf(xpf0);
            xFh[parN][sa] = h0; xFl[parN][sa] = f2bf(xpf0 - bf2f(h0));
            int sb = (pj1 >> 5) * 512 + ((pj1 >> 3) & 3) * 128 + pb1 * 8 + (pj1 & 7);
            unsigned short h1 = f2bf(xpf1);
            xFh[parN][sb] = h1; xFl[parN][sb] = f2bf(xpf1 - bf2f(h1));
        }
        __syncthreads();  // syncE (drains vmcnt -> plane stores complete)
        if (s <= 1022 && tid == 0)
            __hip_atomic_store(&flags[g * 16 + ut], (unsigned)(s + 1),
                               __ATOMIC_RELAXED, __HIP_MEMORY_SCOPE_AGENT);
    }
}

extern "C" void kernel_launch(void* const* d_in, const int* in_sizes, int n_in,
                              void* d_out, int out_size, void* d_ws, size_t ws_size,
                              hipStream_t stream)
{
    const float* x    = (const float*)d_in[0];
    const float* W_ih = (const float*)d_in[1];
    const float* W_hh = (const float*)d_in[2];
    const float* b_ih = (const float*)d_in[3];
    const float* b_hh = (const float*)d_in[4];
    const float* W1   = (const float*)d_in[5];
    const float* b1   = (const float*)d_in[6];
    const float* W2   = (const float*)d_in[7];
    const float* b2   = (const float*)d_in[8];
    const float* W3   = (const float*)d_in[9];
    const float* b3   = (const float*)d_in[10];
    float* out = (float*)d_out;
    float* ws  = (float*)d_ws;

    hipMemsetAsync(ws, 0, 131072, stream);                   // hi plane parity 0
    hipMemsetAsync((char*)ws + 262144, 0, 131072, stream);   // lo plane parity 0
    hipMemsetAsync((char*)ws + 524288, 0, 1024, stream);     // flags
    prep_pack<<<254, 256, 0, stream>>>(W1, W2, W3, ws);
    mdn_rnn_persist<<<256, 512, 0, stream>>>(x, W_ih, W_hh, b_ih, b_hh,
                                             b1, b2, b3, ws, out);
}